// Round 18
// baseline (1803.720 us; speedup 1.0000x reference)
//
#include <hip/hip_runtime.h>
#include <hip/hip_bf16.h>

// AttentionForQuantizer: q/k/v proj + RMSNorm + logits(32768x4096) + argmax + gather.
// R18: LAST-FINISHER FUSION (4 -> 3 nodes). mfma internals reverted to R14's proven
// form (R17 pipeline closed: -2 occupancy > pipeline gain, matching guide m99/m100).
// New: per-row-band (128 rows) atomic counter (zeroed by rmsnorm_fused each launch ->
// deterministic; rmsnorm completes before mfma in-stream). Each mfma block: stores ->
// __threadfence -> atomicAdd; the 32nd (last) block of a band re-fences and runs the
// VERBATIM refine body (frozen dot256_f32, same thresholds on same stored values ->
// bit-identical idx/z_q) for its 128 rows, 32 iterations of the proven 4-row pattern
// (cnt/list are per-wave -> loop-safe). Removes refine's ~140us wall + ~21us node G;
// finisher tails overlap remaining mfma blocks. Canary: absmax == 0.03125.

#define NTOK 32768
#define NCODE 4096
#define DIM 256

typedef __bf16 bf16x8 __attribute__((ext_vector_type(8)));
typedef float f32x4 __attribute__((ext_vector_type(4)));

__device__ __forceinline__ void nt_store4(const float4& v, float* p) {
    f32x4 w; w[0] = v.x; w[1] = v.y; w[2] = v.z; w[3] = v.w;
    __builtin_nontemporal_store(w, (f32x4*)p);
}

// ---------------- fused fp32 GEMMs: k, v, q projections in one dispatch ----------------
// Byte-identical to R14 (passed). Grid (320, 2).
__global__ __launch_bounds__(256, 2)
void gemm_fused(const float* __restrict__ hs, const float* __restrict__ cb,
                const float* __restrict__ wq, const float* __restrict__ bq,
                const float* __restrict__ wk, const float* __restrict__ bk,
                const float* __restrict__ wv, const float* __restrict__ bv,
                float* __restrict__ qf, float* __restrict__ kf, float* __restrict__ vf)
{
    __shared__ __align__(16) float Xs[32][132];  // [kk][m], padded
    __shared__ __align__(16) float Ws[32][132];  // [kk][n], padded
    const int t  = threadIdx.x;
    const int tm = t >> 4;         // 0..15
    const int tn = t & 15;         // 0..15

    const int bx = blockIdx.x;
    const float* X; const float* W; const float* bias; float* Y; int mb;
    if (bx < 32)      { X = cb; W = wk; bias = bk; Y = kf; mb = bx * 128; }
    else if (bx < 64) { X = cb; W = wv; bias = bv; Y = vf; mb = (bx - 32) * 128; }
    else              { X = hs; W = wq; bias = bq; Y = qf; mb = (bx - 64) * 128; }
    const int nb = blockIdx.y * 128;

    float acc[8][8];
    #pragma unroll
    for (int i = 0; i < 8; ++i)
        #pragma unroll
        for (int j = 0; j < 8; ++j) acc[i][j] = 0.f;

    const int sxm = t >> 1;          // X staging: row 0..127
    const int sxh = (t & 1) * 16;    // X staging: k-half base
    const int swk = t >> 3;          // W staging: kk 0..31
    const int swc = (t & 7) * 16;    // W staging: col base

    for (int kb = 0; kb < 256; kb += 32) {
        float4 xv[4], wv4[4];
        #pragma unroll
        for (int i = 0; i < 4; ++i) {
            xv[i]  = *(const float4*)&X[(size_t)(mb + sxm) * 256 + kb + sxh + 4 * i];
            wv4[i] = *(const float4*)&W[(size_t)(kb + swk) * 256 + nb + swc + 4 * i];
        }
        __syncthreads();  // previous iteration's LDS reads done before overwrite
        #pragma unroll
        for (int i = 0; i < 4; ++i) {
            Xs[sxh + 4*i + 0][sxm] = xv[i].x;
            Xs[sxh + 4*i + 1][sxm] = xv[i].y;
            Xs[sxh + 4*i + 2][sxm] = xv[i].z;
            Xs[sxh + 4*i + 3][sxm] = xv[i].w;
            *(float4*)&Ws[swk][swc + 4*i] = wv4[i];
        }
        __syncthreads();
        #pragma unroll 8
        for (int kk = 0; kk < 32; ++kk) {
            float4 a0 = *(const float4*)&Xs[kk][tm*8];
            float4 a1 = *(const float4*)&Xs[kk][tm*8 + 4];
            float4 b0 = *(const float4*)&Ws[kk][tn*8];
            float4 b1 = *(const float4*)&Ws[kk][tn*8 + 4];
            float av[8] = {a0.x,a0.y,a0.z,a0.w,a1.x,a1.y,a1.z,a1.w};
            float bw[8] = {b0.x,b0.y,b0.z,b0.w,b1.x,b1.y,b1.z,b1.w};
            #pragma unroll
            for (int i = 0; i < 8; ++i)
                #pragma unroll
                for (int j = 0; j < 8; ++j)
                    acc[i][j] = fmaf(av[i], bw[j], acc[i][j]);
        }
    }

    float4 bb0 = *(const float4*)&bias[nb + tn*8];
    float4 bb1 = *(const float4*)&bias[nb + tn*8 + 4];
    float bb[8] = {bb0.x,bb0.y,bb0.z,bb0.w,bb1.x,bb1.y,bb1.z,bb1.w};
    #pragma unroll
    for (int i = 0; i < 8; ++i) {
        const size_t row = (size_t)(mb + tm*8 + i);
        float4 o0 = {acc[i][0]+bb[0], acc[i][1]+bb[1], acc[i][2]+bb[2], acc[i][3]+bb[3]};
        float4 o1 = {acc[i][4]+bb[4], acc[i][5]+bb[5], acc[i][6]+bb[6], acc[i][7]+bb[7]};
        *(float4*)&Y[row*256 + nb + tn*8]     = o0;
        *(float4*)&Y[row*256 + nb + tn*8 + 4] = o1;
    }
}

// ---------------- fused RMSNorm: k rows + q rows in one dispatch + counter zeroing ----
// Body identical to R14 (passed); block 0 additionally zeroes the 256 band counters
// (completes before mfma starts -> counters deterministic each launch/graph replay).
__global__ __launch_bounds__(256)
void rmsnorm_fused(float* __restrict__ kf, float* __restrict__ qf,
                   const float* __restrict__ gk, const float* __restrict__ gq,
                   __hip_bfloat16* __restrict__ kb, __hip_bfloat16* __restrict__ qb,
                   int* __restrict__ bandCnt)
{
    const int b = blockIdx.x;
    if (b == 0) bandCnt[threadIdx.x] = 0;   // 256 counters

    float* X; const float* g; __hip_bfloat16* Xb; size_t row;
    if (b < 1024) { X = kf; g = gk; Xb = kb; row = (size_t)b * 4 + (threadIdx.x >> 6); }
    else { X = qf; g = gq; Xb = qb; row = (size_t)(b - 1024) * 4 + (threadIdx.x >> 6); }

    const int lane = threadIdx.x & 63;
    float4 x = *(const float4*)&X[row*256 + lane*4];
    float ssq = fmaf(x.x, x.x, fmaf(x.y, x.y, fmaf(x.z, x.z, x.w * x.w)));
    #pragma unroll
    for (int o = 1; o < 64; o <<= 1) ssq += __shfl_xor(ssq, o, 64);
    const float r = 1.0f / sqrtf(ssq * (1.0f/256.0f) + 1e-5f);
    float4 gg = *(const float4*)&g[lane*4];
    float y0 = (x.x*r)*gg.x, y1 = (x.y*r)*gg.y, y2 = (x.z*r)*gg.z, y3 = (x.w*r)*gg.w;
    float4 y = {y0, y1, y2, y3};
    *(float4*)&X[row*256 + lane*4] = y;
    __hip_bfloat16 h0 = __float2bfloat16(y0), h1 = __float2bfloat16(y1);
    __hip_bfloat16 h2 = __float2bfloat16(y2), h3 = __float2bfloat16(y3);
    ushort4 p;
    p.x = *(unsigned short*)&h0; p.y = *(unsigned short*)&h1;
    p.z = *(unsigned short*)&h2; p.w = *(unsigned short*)&h3;
    ((ushort4*)Xb)[row*64 + lane] = p;
}

// ---------------- FROZEN canonical fp32 dot (argmax determinism anchor) ----------------
// DO NOT change the summation structure. R3..R17 PASSED with this exact sequence.
__device__ __forceinline__ float dot256_f32(const float* __restrict__ a, const float* __restrict__ b)
{
    float s0 = 0.f, s1 = 0.f, s2 = 0.f, s3 = 0.f;
    #pragma unroll 8
    for (int j = 0; j < 64; ++j) {
        float4 x = ((const float4*)a)[j];
        float4 y = ((const float4*)b)[j];
        s0 = fmaf(x.x, y.x, s0);
        s1 = fmaf(x.y, y.y, s1);
        s2 = fmaf(x.z, y.z, s2);
        s3 = fmaf(x.w, y.w, s3);
    }
    return (s0 + s1) + (s2 + s3);
}

// ---------------- bf16 MFMA logits + last-finisher refine ----------------
// K-loop / staging / epilogue / Tmax byte-identical to R14 (passed). Tail: fence ->
// atomicAdd(bandCnt); the 32nd block of a band runs the verbatim refine body for its
// 128 rows (32 x 4-row iterations; cnt/list per-wave so loop needs no extra sync).
__device__ __forceinline__ void load_lds16(const void* g, void* l) {
    __builtin_amdgcn_global_load_lds((const __attribute__((address_space(1))) unsigned int*)g,
                                     (__attribute__((address_space(3))) unsigned int*)l, 16, 0, 0);
}

__global__ __launch_bounds__(256, 4)
void mfma_logits_refine(const __hip_bfloat16* __restrict__ Qb, const __hip_bfloat16* __restrict__ Kb,
                        float* __restrict__ Out, float* __restrict__ Tmax,
                        int* __restrict__ bandCnt,
                        const float* __restrict__ Qf, const float* __restrict__ Kf,
                        const float* __restrict__ Vf, float* __restrict__ OutIdx,
                        float* __restrict__ Zq, float* __restrict__ Zq2)
{
    // 33KB (R14 layout) + 4KB refine lists + cnts
    __shared__ __align__(16) char smem[37904];
    __hip_bfloat16* Asm = (__hip_bfloat16*)smem;            // [128][64] bf16, 16KB
    __hip_bfloat16* Bsm = (__hip_bfloat16*)(smem + 16384);  // [128][64] bf16, 16KB
    float*          Eps  = (float*)smem;                    // [64][128] fp32 (aliases)
    float*          Pmax = (float*)(smem + 32768);          // 1KB
    int*            rcnt  = (int*)(smem + 33792);           // [4]
    int*            rlist = (int*)(smem + 33808);           // [4][256]
    __shared__ int isLast;

    const int t    = threadIdx.x;
    const int lane = t & 63;
    const int w    = t >> 6;
    const int wm = w >> 1, wn = w & 1;      // 2x2 wave grid of 64x64 quadrants

    const int bid = blockIdx.x;
    const int xcd = bid & 7;
    const int cid = bid >> 3;                // 0..1023
    const int band = xcd * 32 + (cid & 31);  // row-band 0..255
    const int mb  = band * 128;
    const int ctl = cid >> 5;                // col-tile 0..31
    const int nb  = ctl * 128;

    const int grow   = t >> 3;                       // + i*32 per issue
    const int gslot  = (t & 7) ^ ((t >> 3) & 7);     // involution, row-local
    const __hip_bfloat16* gA = Qb + (size_t)(mb + grow) * 256 + gslot * 8;
    const __hip_bfloat16* gB = Kb + (size_t)(nb + grow) * 256 + gslot * 8;
    __hip_bfloat16* lA = &Asm[w * 512];              // + i*2048 per issue
    __hip_bfloat16* lB = &Bsm[w * 512];

    const int fr = lane & 15;
    const int kq = lane >> 4;
    const int rswz = lane & 7;
    const int ra0 = (wm * 64 + fr) * 64;
    const int rb0 = (wn * 64 + fr) * 64;

    f32x4 acc[4][4];
    #pragma unroll
    for (int mi = 0; mi < 4; ++mi)
        #pragma unroll
        for (int ni = 0; ni < 4; ++ni) {
            acc[mi][ni][0] = 0.f; acc[mi][ni][1] = 0.f;
            acc[mi][ni][2] = 0.f; acc[mi][ni][3] = 0.f;
        }

    for (int ks = 0; ks < 4; ++ks) {
        const int k0 = ks * 64;
        #pragma unroll
        for (int i = 0; i < 4; ++i) {
            load_lds16(gA + (size_t)i * 32 * 256 + k0, lA + i * 2048);
            load_lds16(gB + (size_t)i * 32 * 256 + k0, lB + i * 2048);
        }
        __syncthreads();   // compiler drains vmcnt(0) before s_barrier [m97 evidence]

        #pragma unroll
        for (int kh = 0; kh < 2; ++kh) {            // ascending k == R4..R17 order
            bf16x8 af[4], bg[4];
            #pragma unroll
            for (int mi = 0; mi < 4; ++mi)
                af[mi] = *(const bf16x8*)&Asm[ra0 + mi*16*64 + (((kh<<2) + kq) ^ rswz) * 8];
            #pragma unroll
            for (int ni = 0; ni < 4; ++ni)
                bg[ni] = *(const bf16x8*)&Bsm[rb0 + ni*16*64 + (((kh<<2) + kq) ^ rswz) * 8];
            #pragma unroll
            for (int mi = 0; mi < 4; ++mi)
                #pragma unroll
                for (int ni = 0; ni < 4; ++ni)
                    acc[mi][ni] = __builtin_amdgcn_mfma_f32_16x16x32_bf16(
                        af[mi], bg[ni], acc[mi][ni], 0, 0, 0);
        }
        __syncthreads();
    }

    // ---- per-row partial maxima (row = wm*64+mi*16+(lane>>4)*4+j) ----
    #pragma unroll
    for (int mi = 0; mi < 4; ++mi)
        #pragma unroll
        for (int j = 0; j < 4; ++j) {
            float mx = fmaxf(fmaxf(acc[mi][0][j], acc[mi][1][j]),
                             fmaxf(acc[mi][2][j], acc[mi][3][j]));
            #pragma unroll
            for (int o = 1; o < 16; o <<= 1) mx = fmaxf(mx, __shfl_xor(mx, o, 64));
            if ((lane & 15) == 0)
                Pmax[(wm*64 + mi*16 + (lane>>4)*4 + j)*2 + wn] = mx;
        }

    // ---- epilogue: LDS bounce -> coalesced dwordx4 NONTEMPORAL stores ----
    const int cr = (lane >> 4) * 4;
    const int cc = lane & 15;
    #pragma unroll
    for (int c = 0; c < 2; ++c) {
        if (wm == c) {
            #pragma unroll
            for (int mi = 0; mi < 4; ++mi)
                #pragma unroll
                for (int ni = 0; ni < 4; ++ni) {
                    const int lrow = mi*16 + cr;
                    const int lcol = wn*64 + ni*16 + cc;
                    #pragma unroll
                    for (int j = 0; j < 4; ++j) {
                        float v = acc[mi][ni][j] * 0.0625f;
                        v = fminf(fmaxf(v, -16.0f), 16.0f);
                        Eps[(lrow + j) * 128 + lcol] = v;
                    }
                }
        }
        __syncthreads();
        #pragma unroll
        for (int it = 0; it < 8; ++it) {
            const int p   = it * 1024 + t * 4;
            const int row = p >> 7;
            const int col = p & 127;
            float4 v = *(const float4*)&Eps[p];
            nt_store4(v, &Out[(size_t)(mb + c*64 + row) * 4096 + nb + col]);
        }
        __syncthreads();
    }

    // ---- Tmax (monotone under clamp-scale -> equals max of stored values) ----
    if (t < 128) {
        float raw = fmaxf(Pmax[t*2], Pmax[t*2 + 1]);
        float v = raw * 0.0625f;
        v = fminf(fmaxf(v, -16.0f), 16.0f);
        Tmax[(size_t)(mb + t) * 32 + ctl] = v;
    }

    // ---- last-finisher handoff ----
    __threadfence();                       // release: logits + Tmax visible device-wide
    if (t == 0) {
        int old = atomicAdd(&bandCnt[band], 1);
        isLast = (old == 31) ? 1 : 0;
    }
    __syncthreads();
    if (!isLast) return;
    __threadfence();                       // acquire side

    // ---- verbatim refine body (R8..R17 proven), 32 x 4-row iterations ----
    #pragma unroll 1
    for (int rr = 0; rr < 32; ++rr) {
        const size_t row = (size_t)mb + rr*4 + w;

        float tm = (lane < 32) ? Tmax[row * 32 + lane] : -INFINITY;
        float gmax = tm;
        #pragma unroll
        for (int o = 1; o < 64; o <<= 1) gmax = fmaxf(gmax, __shfl_xor(gmax, o, 64));
        const float thr = gmax - 0.5f;

        if (lane == 0) rcnt[w] = 0;
        __syncthreads();

        for (int tile = 0; tile < 32; ++tile) {
            const float tmt = __shfl(tm, tile, 64);
            if (tmt >= thr) {
                const float2 v2 = *(const float2*)&Out[row * 4096 + tile * 128 + lane * 2];
                if (v2.x >= thr) {
                    int slot = atomicAdd(&rcnt[w], 1);
                    if (slot < 256) rlist[w*256 + slot] = tile*128 + lane*2;
                }
                if (v2.y >= thr) {
                    int slot = atomicAdd(&rcnt[w], 1);
                    if (slot < 256) rlist[w*256 + slot] = tile*128 + lane*2 + 1;
                }
            }
        }
        __syncthreads();

        int m = rcnt[w]; if (m > 256) m = 256;
        float bv = -INFINITY;
        int   bi = 0x7fffffff;
        const float* qrow = Qf + row * 256;
        for (int base = 0; base < m; base += 64) {
            const int ci = base + lane;
            if (ci < m) {
                const int c = rlist[w*256 + ci];
                float rv = dot256_f32(qrow, Kf + (size_t)c * 256) * 0.0625f;
                if (rv > bv || (rv == bv && c < bi)) { bv = rv; bi = c; }
            }
        }
        #pragma unroll
        for (int o = 1; o < 64; o <<= 1) {
            float ov = __shfl_xor(bv, o, 64);
            int   oi = __shfl_xor(bi, o, 64);
            if (ov > bv || (ov == bv && oi < bi)) { bv = ov; bi = oi; }
        }

        if (bi < 0) bi = 0;
        if (bi > 4095) bi = 4095;

        if (lane == 0) __builtin_nontemporal_store((float)bi, &OutIdx[row]);

        float4 vv = ((const float4*)(Vf + (size_t)bi * 256))[lane];
        nt_store4(vv, (float*)&((float4*)Zq)[row*64 + lane]);
        nt_store4(vv, (float*)&((float4*)Zq2)[row*64 + lane]);
        __syncthreads();
    }
}

extern "C" void kernel_launch(void* const* d_in, const int* in_sizes, int n_in,
                              void* d_out, int out_size, void* d_ws, size_t ws_size,
                              hipStream_t stream)
{
    (void)in_sizes; (void)n_in; (void)out_size;
    const float* hs = (const float*)d_in[0];
    const float* cb = (const float*)d_in[1];
    const float* wq = (const float*)d_in[2];
    const float* bq = (const float*)d_in[3];
    const float* wk = (const float*)d_in[4];
    const float* bk = (const float*)d_in[5];
    const float* wv = (const float*)d_in[6];
    const float* bv = (const float*)d_in[7];
    const float* gq = (const float*)d_in[8];
    const float* gk = (const float*)d_in[9];
    float* out = (float*)d_out;   // fp32: reference outputs are fp32/int32

    if (ws_size < 31459328u) return;  // 30MB scratch + counters

    // d_out layout (floats): logits @0, idx @134217728, z_q @134250496, z_q_2 @142639104.
    float* qf = out + 134250496ull;   // q lives in the z_q region until the FINAL refine store

    char* ws = (char*)d_ws;
    float* kf = (float*)ws;                                   //  4 MB
    float* vf = (float*)(ws + 4194304);                       //  4 MB
    __hip_bfloat16* qb = (__hip_bfloat16*)(ws + 8388608);     // 16 MB
    __hip_bfloat16* kb = (__hip_bfloat16*)(ws + 25165824);    //  2 MB
    float* tmax = (float*)(ws + 27262976);                    //  4 MB
    int* bandCnt = (int*)(ws + 31457280);                     //  1 KB (256 ints)

    gemm_fused<<<dim3(320, 2), 256, 0, stream>>>(hs, cb, wq, bq, wk, bk, wv, bv,
                                                 qf, kf, vf);
    rmsnorm_fused<<<9216, 256, 0, stream>>>(kf, qf, gk, gq, kb, qb, bandCnt);
    mfma_logits_refine<<<8192, 256, 0, stream>>>(qb, kb, out, tmax, bandCnt,
        qf, kf, vf,
        out + 134217728ull,   // idx
        out + 134250496ull,   // z_q   (aliases qf by design)
        out + 142639104ull);  // z_q_2
}

// Round 19
// 435.181 us; speedup vs baseline: 4.1448x; 4.1448x over previous
//
#include <hip/hip_runtime.h>
#include <hip/hip_bf16.h>

// AttentionForQuantizer: q/k/v proj + RMSNorm + logits(32768x4096) + argmax + gather.
// R19: REVERT to R14 (441us proven best; R18's cross-block fence fusion cost 8192
// device-scope L2 writebacks -> 1804us, lane closed). ONE delta: refine phase 2 uses
// a wave-uniform ballot bitmask over candidate tiles (identical compares on identical
// values -> identical candidate set; list order irrelevant since the max-with-min-idx
// reduce is order-independent) instead of the serial 32-iteration shfl+branch scan.
// All else byte-identical to R14 (passed). Canary: absmax == 0.03125.

#define NTOK 32768
#define NCODE 4096
#define DIM 256

typedef __bf16 bf16x8 __attribute__((ext_vector_type(8)));
typedef float f32x4 __attribute__((ext_vector_type(4)));

__device__ __forceinline__ void nt_store4(const float4& v, float* p) {
    f32x4 w; w[0] = v.x; w[1] = v.y; w[2] = v.z; w[3] = v.w;
    __builtin_nontemporal_store(w, (f32x4*)p);
}

// ---------------- fused fp32 GEMMs: k, v, q projections in one dispatch ----------------
// Byte-identical to R14 (passed). Grid (320, 2).
__global__ __launch_bounds__(256, 2)
void gemm_fused(const float* __restrict__ hs, const float* __restrict__ cb,
                const float* __restrict__ wq, const float* __restrict__ bq,
                const float* __restrict__ wk, const float* __restrict__ bk,
                const float* __restrict__ wv, const float* __restrict__ bv,
                float* __restrict__ qf, float* __restrict__ kf, float* __restrict__ vf)
{
    __shared__ __align__(16) float Xs[32][132];  // [kk][m], padded
    __shared__ __align__(16) float Ws[32][132];  // [kk][n], padded
    const int t  = threadIdx.x;
    const int tm = t >> 4;         // 0..15
    const int tn = t & 15;         // 0..15

    const int bx = blockIdx.x;
    const float* X; const float* W; const float* bias; float* Y; int mb;
    if (bx < 32)      { X = cb; W = wk; bias = bk; Y = kf; mb = bx * 128; }
    else if (bx < 64) { X = cb; W = wv; bias = bv; Y = vf; mb = (bx - 32) * 128; }
    else              { X = hs; W = wq; bias = bq; Y = qf; mb = (bx - 64) * 128; }
    const int nb = blockIdx.y * 128;

    float acc[8][8];
    #pragma unroll
    for (int i = 0; i < 8; ++i)
        #pragma unroll
        for (int j = 0; j < 8; ++j) acc[i][j] = 0.f;

    const int sxm = t >> 1;          // X staging: row 0..127
    const int sxh = (t & 1) * 16;    // X staging: k-half base
    const int swk = t >> 3;          // W staging: kk 0..31
    const int swc = (t & 7) * 16;    // W staging: col base

    for (int kb = 0; kb < 256; kb += 32) {
        float4 xv[4], wv4[4];
        #pragma unroll
        for (int i = 0; i < 4; ++i) {
            xv[i]  = *(const float4*)&X[(size_t)(mb + sxm) * 256 + kb + sxh + 4 * i];
            wv4[i] = *(const float4*)&W[(size_t)(kb + swk) * 256 + nb + swc + 4 * i];
        }
        __syncthreads();  // previous iteration's LDS reads done before overwrite
        #pragma unroll
        for (int i = 0; i < 4; ++i) {
            Xs[sxh + 4*i + 0][sxm] = xv[i].x;
            Xs[sxh + 4*i + 1][sxm] = xv[i].y;
            Xs[sxh + 4*i + 2][sxm] = xv[i].z;
            Xs[sxh + 4*i + 3][sxm] = xv[i].w;
            *(float4*)&Ws[swk][swc + 4*i] = wv4[i];
        }
        __syncthreads();
        #pragma unroll 8
        for (int kk = 0; kk < 32; ++kk) {
            float4 a0 = *(const float4*)&Xs[kk][tm*8];
            float4 a1 = *(const float4*)&Xs[kk][tm*8 + 4];
            float4 b0 = *(const float4*)&Ws[kk][tn*8];
            float4 b1 = *(const float4*)&Ws[kk][tn*8 + 4];
            float av[8] = {a0.x,a0.y,a0.z,a0.w,a1.x,a1.y,a1.z,a1.w};
            float bw[8] = {b0.x,b0.y,b0.z,b0.w,b1.x,b1.y,b1.z,b1.w};
            #pragma unroll
            for (int i = 0; i < 8; ++i)
                #pragma unroll
                for (int j = 0; j < 8; ++j)
                    acc[i][j] = fmaf(av[i], bw[j], acc[i][j]);
        }
    }

    float4 bb0 = *(const float4*)&bias[nb + tn*8];
    float4 bb1 = *(const float4*)&bias[nb + tn*8 + 4];
    float bb[8] = {bb0.x,bb0.y,bb0.z,bb0.w,bb1.x,bb1.y,bb1.z,bb1.w};
    #pragma unroll
    for (int i = 0; i < 8; ++i) {
        const size_t row = (size_t)(mb + tm*8 + i);
        float4 o0 = {acc[i][0]+bb[0], acc[i][1]+bb[1], acc[i][2]+bb[2], acc[i][3]+bb[3]};
        float4 o1 = {acc[i][4]+bb[4], acc[i][5]+bb[5], acc[i][6]+bb[6], acc[i][7]+bb[7]};
        *(float4*)&Y[row*256 + nb + tn*8]     = o0;
        *(float4*)&Y[row*256 + nb + tn*8 + 4] = o1;
    }
}

// ---------------- fused RMSNorm: k rows + q rows in one dispatch ----------------
// Byte-identical to R14 (passed). Grid 9216.
__global__ __launch_bounds__(256)
void rmsnorm_fused(float* __restrict__ kf, float* __restrict__ qf,
                   const float* __restrict__ gk, const float* __restrict__ gq,
                   __hip_bfloat16* __restrict__ kb, __hip_bfloat16* __restrict__ qb)
{
    const int b = blockIdx.x;
    float* X; const float* g; __hip_bfloat16* Xb; size_t row;
    if (b < 1024) { X = kf; g = gk; Xb = kb; row = (size_t)b * 4 + (threadIdx.x >> 6); }
    else { X = qf; g = gq; Xb = qb; row = (size_t)(b - 1024) * 4 + (threadIdx.x >> 6); }

    const int lane = threadIdx.x & 63;
    float4 x = *(const float4*)&X[row*256 + lane*4];
    float ssq = fmaf(x.x, x.x, fmaf(x.y, x.y, fmaf(x.z, x.z, x.w * x.w)));
    #pragma unroll
    for (int o = 1; o < 64; o <<= 1) ssq += __shfl_xor(ssq, o, 64);
    const float r = 1.0f / sqrtf(ssq * (1.0f/256.0f) + 1e-5f);
    float4 gg = *(const float4*)&g[lane*4];
    float y0 = (x.x*r)*gg.x, y1 = (x.y*r)*gg.y, y2 = (x.z*r)*gg.z, y3 = (x.w*r)*gg.w;
    float4 y = {y0, y1, y2, y3};
    *(float4*)&X[row*256 + lane*4] = y;
    __hip_bfloat16 h0 = __float2bfloat16(y0), h1 = __float2bfloat16(y1);
    __hip_bfloat16 h2 = __float2bfloat16(y2), h3 = __float2bfloat16(y3);
    ushort4 p;
    p.x = *(unsigned short*)&h0; p.y = *(unsigned short*)&h1;
    p.z = *(unsigned short*)&h2; p.w = *(unsigned short*)&h3;
    ((ushort4*)Xb)[row*64 + lane] = p;
}

// ---------------- bf16 MFMA logits: Out[32768][4096] = fp32(clamp(Q @ K^T * 1/16)) ----
// Byte-identical to R14 (passed): m97 loop, both-sides LDS swizzle, LDS-bounce epilogue
// with NONTEMPORAL logits stores, Tmax emission, lb(256,4), XCD-chunked grid.
__device__ __forceinline__ void load_lds16(const void* g, void* l) {
    __builtin_amdgcn_global_load_lds((const __attribute__((address_space(1))) unsigned int*)g,
                                     (__attribute__((address_space(3))) unsigned int*)l, 16, 0, 0);
}

__global__ __launch_bounds__(256, 4)
void mfma_logits(const __hip_bfloat16* __restrict__ Qb, const __hip_bfloat16* __restrict__ Kb,
                 float* __restrict__ Out, float* __restrict__ Tmax)
{
    __shared__ __align__(16) char smem[33792];
    __hip_bfloat16* Asm = (__hip_bfloat16*)smem;            // [128 rows][64 k] bf16, 16KB
    __hip_bfloat16* Bsm = (__hip_bfloat16*)(smem + 16384);  // [128 rows][64 k] bf16, 16KB
    float*          Eps = (float*)smem;                     // [64 rows][128 cols] fp32, 32KB
    float*          Pmax = (float*)(smem + 32768);          // [128 rows][2 halves], 1KB

    const int t    = threadIdx.x;
    const int lane = t & 63;
    const int w    = t >> 6;
    const int wm = w >> 1, wn = w & 1;      // 2x2 wave grid of 64x64 quadrants

    const int bid = blockIdx.x;
    const int xcd = bid & 7;
    const int cid = bid >> 3;                // 0..1023
    const int mb  = (xcd * 32 + (cid & 31)) * 128;
    const int ctl = cid >> 5;                // col-tile 0..31
    const int nb  = ctl * 128;

    const int grow   = t >> 3;                       // + i*32 per issue
    const int gslot  = (t & 7) ^ ((t >> 3) & 7);     // involution, row-local
    const __hip_bfloat16* gA = Qb + (size_t)(mb + grow) * 256 + gslot * 8;
    const __hip_bfloat16* gB = Kb + (size_t)(nb + grow) * 256 + gslot * 8;
    __hip_bfloat16* lA = &Asm[w * 512];              // + i*2048 per issue (bf16 elems)
    __hip_bfloat16* lB = &Bsm[w * 512];

    const int fr = lane & 15;
    const int kq = lane >> 4;
    const int rswz = lane & 7;                       // row&7 for all our fragment rows
    const int ra0 = (wm * 64 + fr) * 64;             // A base elem offset (row*64)
    const int rb0 = (wn * 64 + fr) * 64;

    f32x4 acc[4][4];
    #pragma unroll
    for (int mi = 0; mi < 4; ++mi)
        #pragma unroll
        for (int ni = 0; ni < 4; ++ni) {
            acc[mi][ni][0] = 0.f; acc[mi][ni][1] = 0.f;
            acc[mi][ni][2] = 0.f; acc[mi][ni][3] = 0.f;
        }

    for (int ks = 0; ks < 4; ++ks) {
        const int k0 = ks * 64;
        #pragma unroll
        for (int i = 0; i < 4; ++i) {
            load_lds16(gA + (size_t)i * 32 * 256 + k0, lA + i * 2048);
            load_lds16(gB + (size_t)i * 32 * 256 + k0, lB + i * 2048);
        }
        __syncthreads();   // compiler drains vmcnt(0) before s_barrier [m97 evidence]

        #pragma unroll
        for (int kh = 0; kh < 2; ++kh) {            // ascending k == R4..R14 order
            bf16x8 af[4], bg[4];
            #pragma unroll
            for (int mi = 0; mi < 4; ++mi)
                af[mi] = *(const bf16x8*)&Asm[ra0 + mi*16*64 + (((kh<<2) + kq) ^ rswz) * 8];
            #pragma unroll
            for (int ni = 0; ni < 4; ++ni)
                bg[ni] = *(const bf16x8*)&Bsm[rb0 + ni*16*64 + (((kh<<2) + kq) ^ rswz) * 8];
            #pragma unroll
            for (int mi = 0; mi < 4; ++mi)
                #pragma unroll
                for (int ni = 0; ni < 4; ++ni)
                    acc[mi][ni] = __builtin_amdgcn_mfma_f32_16x16x32_bf16(
                        af[mi], bg[ni], acc[mi][ni], 0, 0, 0);
        }
        __syncthreads();   // LDS reads done before next K-step overwrites / epilogue
    }

    // ---- per-row partial maxima from acc regs (row = wm*64+mi*16+(lane>>4)*4+j) ----
    #pragma unroll
    for (int mi = 0; mi < 4; ++mi)
        #pragma unroll
        for (int j = 0; j < 4; ++j) {
            float mx = fmaxf(fmaxf(acc[mi][0][j], acc[mi][1][j]),
                             fmaxf(acc[mi][2][j], acc[mi][3][j]));
            #pragma unroll
            for (int o = 1; o < 16; o <<= 1) mx = fmaxf(mx, __shfl_xor(mx, o, 64));
            if ((lane & 15) == 0)
                Pmax[(wm*64 + mi*16 + (lane>>4)*4 + j)*2 + wn] = mx;
        }

    // ---- epilogue: LDS bounce -> coalesced full-row dwordx4 NONTEMPORAL stores ----
    const int cr = (lane >> 4) * 4;
    const int cc = lane & 15;
    #pragma unroll
    for (int c = 0; c < 2; ++c) {                    // chunk: rows [c*64, c*64+64)
        if (wm == c) {
            #pragma unroll
            for (int mi = 0; mi < 4; ++mi)
                #pragma unroll
                for (int ni = 0; ni < 4; ++ni) {
                    const int lrow = mi*16 + cr;                  // 0..63 within chunk
                    const int lcol = wn*64 + ni*16 + cc;          // 0..127
                    #pragma unroll
                    for (int j = 0; j < 4; ++j) {
                        float v = acc[mi][ni][j] * 0.0625f;
                        v = fminf(fmaxf(v, -16.0f), 16.0f);
                        Eps[(lrow + j) * 128 + lcol] = v;
                    }
                }
        }
        __syncthreads();   // bounce tile (and, first pass, Pmax) complete
        #pragma unroll
        for (int it = 0; it < 8; ++it) {
            const int p   = it * 1024 + t * 4;       // linear word index in [64][128]
            const int row = p >> 7;
            const int col = p & 127;
            float4 v = *(const float4*)&Eps[p];
            nt_store4(v, &Out[(size_t)(mb + c*64 + row) * 4096 + nb + col]);
        }
        __syncthreads();   // chunk read done before next chunk overwrites
    }

    // ---- Tmax: max is monotone under clamp(0.0625*x) -> equals max of stored values.
    // Tmax is re-read by refine -> stays cached (no nt).
    if (t < 128) {
        float raw = fmaxf(Pmax[t*2], Pmax[t*2 + 1]);
        float v = raw * 0.0625f;
        v = fminf(fmaxf(v, -16.0f), 16.0f);
        Tmax[(size_t)(mb + t) * 32 + ctl] = v;
    }
}

// ---------------- FROZEN canonical fp32 dot (argmax determinism anchor) ----------------
// DO NOT change the summation structure. R3..R18 PASSED with this exact sequence.
__device__ __forceinline__ float dot256_f32(const float* __restrict__ a, const float* __restrict__ b)
{
    float s0 = 0.f, s1 = 0.f, s2 = 0.f, s3 = 0.f;
    #pragma unroll 8
    for (int j = 0; j < 64; ++j) {
        float4 x = ((const float4*)a)[j];
        float4 y = ((const float4*)b)[j];
        s0 = fmaf(x.x, y.x, s0);
        s1 = fmaf(x.y, y.y, s1);
        s2 = fmaf(x.z, y.z, s2);
        s3 = fmaf(x.w, y.w, s3);
    }
    return (s0 + s1) + (s2 + s3);
}

// ---------------- refine (fast): Tmax-pruned candidate scan + frozen dots ----------------
// R19 delta: phase 2 iterates a wave-uniform ballot bitmask of candidate tiles
// (identical compares on identical values -> identical candidate set; uniform loop,
// ~2-5 iterations) instead of the serial 32-iteration shfl+branch scan. Phase 1/3 and
// nt stores byte-identical to R14 (passed).
__global__ __launch_bounds__(256)
void refine_argmax_fast(const float* __restrict__ L, const float* __restrict__ Tmax,
                        const float* __restrict__ Qf, const float* __restrict__ Kf,
                        const float* __restrict__ Vf, float* __restrict__ OutIdx,
                        float* __restrict__ Zq, float* __restrict__ Zq2)
{
    __shared__ int cnt[4];
    __shared__ int list[4][256];
    const int lane = threadIdx.x & 63;
    const int w    = threadIdx.x >> 6;
    const size_t row = (size_t)blockIdx.x * 4 + w;

    // phase 1: row max from 32 tile maxima
    float tm = (lane < 32) ? Tmax[row * 32 + lane] : -INFINITY;
    float gmax = tm;
    #pragma unroll
    for (int o = 1; o < 64; o <<= 1) gmax = fmaxf(gmax, __shfl_xor(gmax, o, 64));
    const float thr = gmax - 0.5f;

    if (lane == 0) cnt[w] = 0;
    __syncthreads();   // unconditional

    // phase 2: ballot mask of candidate tiles (lanes 0..31 hold tiles 0..31), then
    // iterate set bits only — wave-uniform, no divergence, same loads & compares.
    unsigned long long cmask = __ballot(tm >= thr);   // lanes >=32: tm = -INF -> false
    while (cmask) {
        const int tile = __ffsll(cmask) - 1;
        cmask &= cmask - 1;
        const float2 v2 = *(const float2*)&L[row * 4096 + tile * 128 + lane * 2];
        if (v2.x >= thr) {
            int slot = atomicAdd(&cnt[w], 1);
            if (slot < 256) list[w][slot] = tile*128 + lane*2;
        }
        if (v2.y >= thr) {
            int slot = atomicAdd(&cnt[w], 1);
            if (slot < 256) list[w][slot] = tile*128 + lane*2 + 1;
        }
    }
    __syncthreads();   // unconditional

    // phase 3: one candidate per lane, all dots in ONE exec pass
    int m = cnt[w]; if (m > 256) m = 256;
    float bv = -INFINITY;
    int   bi = 0x7fffffff;
    const float* qrow = Qf + row * 256;
    for (int base = 0; base < m; base += 64) {
        const int ci = base + lane;
        if (ci < m) {
            const int c = list[w][ci];
            float rv = dot256_f32(qrow, Kf + (size_t)c * 256) * 0.0625f;
            if (rv > bv || (rv == bv && c < bi)) { bv = rv; bi = c; }
        }
    }
    #pragma unroll
    for (int o = 1; o < 64; o <<= 1) {
        float ov = __shfl_xor(bv, o, 64);
        int   oi = __shfl_xor(bi, o, 64);
        if (ov > bv || (ov == bv && oi < bi)) { bv = ov; bi = oi; }
    }

    if (bi < 0) bi = 0;
    if (bi > 4095) bi = 4095;

    if (lane == 0) __builtin_nontemporal_store((float)bi, &OutIdx[row]);

    float4 vv = ((const float4*)(Vf + (size_t)bi * 256))[lane];
    nt_store4(vv, (float*)&((float4*)Zq)[row*64 + lane]);
    nt_store4(vv, (float*)&((float4*)Zq2)[row*64 + lane]);
}

extern "C" void kernel_launch(void* const* d_in, const int* in_sizes, int n_in,
                              void* d_out, int out_size, void* d_ws, size_t ws_size,
                              hipStream_t stream)
{
    (void)in_sizes; (void)n_in; (void)out_size;
    const float* hs = (const float*)d_in[0];
    const float* cb = (const float*)d_in[1];
    const float* wq = (const float*)d_in[2];
    const float* bq = (const float*)d_in[3];
    const float* wk = (const float*)d_in[4];
    const float* bk = (const float*)d_in[5];
    const float* wv = (const float*)d_in[6];
    const float* bv = (const float*)d_in[7];
    const float* gq = (const float*)d_in[8];
    const float* gk = (const float*)d_in[9];
    float* out = (float*)d_out;   // fp32: reference outputs are fp32/int32

    if (ws_size < 31457280u) return;  // need 30MB scratch

    // d_out layout (floats): logits @0 [32768*4096], idx @134217728 [32768],
    // z_q @134250496 [32768*256], z_q_2 @142639104 [32768*256].
    float* qf = out + 134250496ull;   // q lives in the z_q region until the FINAL refine store

    char* ws = (char*)d_ws;
    float* kf = (float*)ws;                                   //  4 MB: k raw -> k_norm (in place)
    float* vf = (float*)(ws + 4194304);                       //  4 MB: v
    __hip_bfloat16* qb = (__hip_bfloat16*)(ws + 8388608);     // 16 MB: q_norm bf16
    __hip_bfloat16* kb = (__hip_bfloat16*)(ws + 25165824);    //  2 MB: k_norm bf16
    float* tmax = (float*)(ws + 27262976);                    //  4 MB: per-tile row max

    gemm_fused<<<dim3(320, 2), 256, 0, stream>>>(hs, cb, wq, bq, wk, bk, wv, bv,
                                                 qf, kf, vf);
    rmsnorm_fused<<<9216, 256, 0, stream>>>(kf, qf, gk, gq, kb, qb);
    mfma_logits<<<8192, 256, 0, stream>>>(qb, kb, out, tmax);
    refine_argmax_fast<<<8192, 256, 0, stream>>>(out, tmax, qf, kf, vf,
        out + 134217728ull,   // idx
        out + 134250496ull,   // z_q   (aliases qf by design)
        out + 142639104ull);  // z_q_2
}

// Round 21
// 423.997 us; speedup vs baseline: 4.2541x; 1.0264x over previous
//
#include <hip/hip_runtime.h>
#include <hip/hip_bf16.h>

// AttentionForQuantizer: q/k/v proj + RMSNorm + logits(32768x4096) + argmax + gather.
// R21: R20 RACE FIX. R20's addressing was correct (re-derived); the failure was raw
// s_barrier NOT draining in-flight ds_reads (unlike __syncthreads, which prefixes
// s_waitcnt lgkmcnt(0) vmcnt(0) — m97 evidence). With MFMA sinking past the barrier
// (guide rule #18), next-iteration global_load_lds staging (into nxt == cur(ks-1)) and
// the Eps epilogue (aliasing A1/B1) could overwrite LDS under in-flight reads. Fix:
// "s_waitcnt lgkmcnt(0)" + sched_barrier(0) before EVERY trailing s_barrier (rule #18
// fence pair). All addressing/values identical to R20 -> bit-identical to R19 outputs.
// gemm/rmsnorm/refine byte-identical to R19 (passed, 435us best). Canary: 0.03125.

#define NTOK 32768
#define NCODE 4096
#define DIM 256

typedef __bf16 bf16x8 __attribute__((ext_vector_type(8)));
typedef float f32x4 __attribute__((ext_vector_type(4)));

__device__ __forceinline__ void nt_store4(const float4& v, float* p) {
    f32x4 w; w[0] = v.x; w[1] = v.y; w[2] = v.z; w[3] = v.w;
    __builtin_nontemporal_store(w, (f32x4*)p);
}

// ---------------- fused fp32 GEMMs: k, v, q projections in one dispatch ----------------
// Byte-identical to R14/R19 (passed). Grid (320, 2).
__global__ __launch_bounds__(256, 2)
void gemm_fused(const float* __restrict__ hs, const float* __restrict__ cb,
                const float* __restrict__ wq, const float* __restrict__ bq,
                const float* __restrict__ wk, const float* __restrict__ bk,
                const float* __restrict__ wv, const float* __restrict__ bv,
                float* __restrict__ qf, float* __restrict__ kf, float* __restrict__ vf)
{
    __shared__ __align__(16) float Xs[32][132];  // [kk][m], padded
    __shared__ __align__(16) float Ws[32][132];  // [kk][n], padded
    const int t  = threadIdx.x;
    const int tm = t >> 4;         // 0..15
    const int tn = t & 15;         // 0..15

    const int bx = blockIdx.x;
    const float* X; const float* W; const float* bias; float* Y; int mb;
    if (bx < 32)      { X = cb; W = wk; bias = bk; Y = kf; mb = bx * 128; }
    else if (bx < 64) { X = cb; W = wv; bias = bv; Y = vf; mb = (bx - 32) * 128; }
    else              { X = hs; W = wq; bias = bq; Y = qf; mb = (bx - 64) * 128; }
    const int nb = blockIdx.y * 128;

    float acc[8][8];
    #pragma unroll
    for (int i = 0; i < 8; ++i)
        #pragma unroll
        for (int j = 0; j < 8; ++j) acc[i][j] = 0.f;

    const int sxm = t >> 1;          // X staging: row 0..127
    const int sxh = (t & 1) * 16;    // X staging: k-half base
    const int swk = t >> 3;          // W staging: kk 0..31
    const int swc = (t & 7) * 16;    // W staging: col base

    for (int kb = 0; kb < 256; kb += 32) {
        float4 xv[4], wv4[4];
        #pragma unroll
        for (int i = 0; i < 4; ++i) {
            xv[i]  = *(const float4*)&X[(size_t)(mb + sxm) * 256 + kb + sxh + 4 * i];
            wv4[i] = *(const float4*)&W[(size_t)(kb + swk) * 256 + nb + swc + 4 * i];
        }
        __syncthreads();  // previous iteration's LDS reads done before overwrite
        #pragma unroll
        for (int i = 0; i < 4; ++i) {
            Xs[sxh + 4*i + 0][sxm] = xv[i].x;
            Xs[sxh + 4*i + 1][sxm] = xv[i].y;
            Xs[sxh + 4*i + 2][sxm] = xv[i].z;
            Xs[sxh + 4*i + 3][sxm] = xv[i].w;
            *(float4*)&Ws[swk][swc + 4*i] = wv4[i];
        }
        __syncthreads();
        #pragma unroll 8
        for (int kk = 0; kk < 32; ++kk) {
            float4 a0 = *(const float4*)&Xs[kk][tm*8];
            float4 a1 = *(const float4*)&Xs[kk][tm*8 + 4];
            float4 b0 = *(const float4*)&Ws[kk][tn*8];
            float4 b1 = *(const float4*)&Ws[kk][tn*8 + 4];
            float av[8] = {a0.x,a0.y,a0.z,a0.w,a1.x,a1.y,a1.z,a1.w};
            float bw[8] = {b0.x,b0.y,b0.z,b0.w,b1.x,b1.y,b1.z,b1.w};
            #pragma unroll
            for (int i = 0; i < 8; ++i)
                #pragma unroll
                for (int j = 0; j < 8; ++j)
                    acc[i][j] = fmaf(av[i], bw[j], acc[i][j]);
        }
    }

    float4 bb0 = *(const float4*)&bias[nb + tn*8];
    float4 bb1 = *(const float4*)&bias[nb + tn*8 + 4];
    float bb[8] = {bb0.x,bb0.y,bb0.z,bb0.w,bb1.x,bb1.y,bb1.z,bb1.w};
    #pragma unroll
    for (int i = 0; i < 8; ++i) {
        const size_t row = (size_t)(mb + tm*8 + i);
        float4 o0 = {acc[i][0]+bb[0], acc[i][1]+bb[1], acc[i][2]+bb[2], acc[i][3]+bb[3]};
        float4 o1 = {acc[i][4]+bb[4], acc[i][5]+bb[5], acc[i][6]+bb[6], acc[i][7]+bb[7]};
        *(float4*)&Y[row*256 + nb + tn*8]     = o0;
        *(float4*)&Y[row*256 + nb + tn*8 + 4] = o1;
    }
}

// ---------------- fused RMSNorm: k rows + q rows in one dispatch ----------------
// Byte-identical to R14/R19 (passed). Grid 9216.
__global__ __launch_bounds__(256)
void rmsnorm_fused(float* __restrict__ kf, float* __restrict__ qf,
                   const float* __restrict__ gk, const float* __restrict__ gq,
                   __hip_bfloat16* __restrict__ kb, __hip_bfloat16* __restrict__ qb)
{
    const int b = blockIdx.x;
    float* X; const float* g; __hip_bfloat16* Xb; size_t row;
    if (b < 1024) { X = kf; g = gk; Xb = kb; row = (size_t)b * 4 + (threadIdx.x >> 6); }
    else { X = qf; g = gq; Xb = qb; row = (size_t)(b - 1024) * 4 + (threadIdx.x >> 6); }

    const int lane = threadIdx.x & 63;
    float4 x = *(const float4*)&X[row*256 + lane*4];
    float ssq = fmaf(x.x, x.x, fmaf(x.y, x.y, fmaf(x.z, x.z, x.w * x.w)));
    #pragma unroll
    for (int o = 1; o < 64; o <<= 1) ssq += __shfl_xor(ssq, o, 64);
    const float r = 1.0f / sqrtf(ssq * (1.0f/256.0f) + 1e-5f);
    float4 gg = *(const float4*)&g[lane*4];
    float y0 = (x.x*r)*gg.x, y1 = (x.y*r)*gg.y, y2 = (x.z*r)*gg.z, y3 = (x.w*r)*gg.w;
    float4 y = {y0, y1, y2, y3};
    *(float4*)&X[row*256 + lane*4] = y;
    __hip_bfloat16 h0 = __float2bfloat16(y0), h1 = __float2bfloat16(y1);
    __hip_bfloat16 h2 = __float2bfloat16(y2), h3 = __float2bfloat16(y3);
    ushort4 p;
    p.x = *(unsigned short*)&h0; p.y = *(unsigned short*)&h1;
    p.z = *(unsigned short*)&h2; p.w = *(unsigned short*)&h3;
    ((ushort4*)Xb)[row*64 + lane] = p;
}

// ---------------- bf16 MFMA logits: Out[32768][4096] = fp32(clamp(Q @ K^T * 1/16)) ----
// R21: BK=32 double-buffered pipeline at occupancy 4, WITH the rule-#18 fence pair
// (lgkmcnt(0) + sched_barrier(0)) before every trailing s_barrier so no wave crosses
// with in-flight ds_reads. Addressing identical to R20; values bit-identical to R19.
__device__ __forceinline__ void load_lds16(const void* g, void* l) {
    __builtin_amdgcn_global_load_lds((const __attribute__((address_space(1))) unsigned int*)g,
                                     (__attribute__((address_space(3))) unsigned int*)l, 16, 0, 0);
}

__global__ __launch_bounds__(256, 4)
void mfma_logits(const __hip_bfloat16* __restrict__ Qb, const __hip_bfloat16* __restrict__ Kb,
                 float* __restrict__ Out, float* __restrict__ Tmax)
{
    // 33KB: A0@0, B0@8192, A1@16384, B1@24576 (8KB each); Eps aliases 0..32KB; Pmax@32KB.
    __shared__ __align__(16) char smem[33792];
    float* Eps  = (float*)smem;
    float* Pmax = (float*)(smem + 32768);

    const int t    = threadIdx.x;
    const int lane = t & 63;
    const int w    = t >> 6;
    const int wm = w >> 1, wn = w & 1;      // 2x2 wave grid of 64x64 quadrants

    const int bid = blockIdx.x;
    const int xcd = bid & 7;
    const int cid = bid >> 3;                // 0..1023
    const int mb  = (xcd * 32 + (cid & 31)) * 128;
    const int ctl = cid >> 5;                // col-tile 0..31
    const int nb  = ctl * 128;

    // staging source (per lane): row w*16 + (lane>>2) (+64 for issue 1),
    // chunk (lane&3)^((lane>>2)&3)  [involution; row&3 == (lane>>2)&3 for all issues]
    const int sr = w*16 + (lane >> 2);
    const int sc = (lane & 3) ^ ((lane >> 2) & 3);
    const __hip_bfloat16* gAr = Qb + (size_t)(mb + sr) * 256 + sc * 8;
    const __hip_bfloat16* gBr = Kb + (size_t)(nb + sr) * 256 + sc * 8;

    // fragment read geometry: row fr, k-chunk kq; swizzled slot kq^(fr&3)
    const int fr = lane & 15;
    const int kq = lane >> 4;
    const int rdsw = (kq ^ (fr & 3)) * 8;
    const int ra0 = (wm * 64 + fr) * 32;
    const int rb0 = (wn * 64 + fr) * 32;

    f32x4 acc[4][4];
    #pragma unroll
    for (int mi = 0; mi < 4; ++mi)
        #pragma unroll
        for (int ni = 0; ni < 4; ++ni) {
            acc[mi][ni][0] = 0.f; acc[mi][ni][1] = 0.f;
            acc[mi][ni][2] = 0.f; acc[mi][ni][3] = 0.f;
        }

    // ---- prologue: stage tile 0 into buf0 ----
    {
        char* dA = smem;            // A0
        char* dB = smem + 8192;     // B0
        load_lds16(gAr,             dA + w*1024);
        load_lds16(gAr + 64*256,    dA + 4096 + w*1024);
        load_lds16(gBr,             dB + w*1024);
        load_lds16(gBr + 64*256,    dB + 4096 + w*1024);
    }

    // ---- 8 pipelined K-steps (k = ks*32, ascending == R19 per-element order) ----
    #pragma unroll
    for (int ks = 0; ks < 8; ++ks) {
        char* curA = (ks & 1) ? (smem + 16384) : smem;
        char* curB = (ks & 1) ? (smem + 24576) : (smem + 8192);
        if (ks < 7) {
            const int k0 = (ks + 1) * 32;
            char* nxtA = (ks & 1) ? smem : (smem + 16384);
            char* nxtB = (ks & 1) ? (smem + 8192) : (smem + 24576);
            load_lds16(gAr + k0,          nxtA + w*1024);
            load_lds16(gAr + 64*256 + k0, nxtA + 4096 + w*1024);
            load_lds16(gBr + k0,          nxtB + w*1024);
            load_lds16(gBr + 64*256 + k0, nxtB + 4096 + w*1024);
            asm volatile("s_waitcnt vmcnt(4)" ::: "memory");  // current tile landed
        } else {
            asm volatile("s_waitcnt vmcnt(0)" ::: "memory");  // final tile landed
        }
        __builtin_amdgcn_s_barrier();

        const __hip_bfloat16* A = (const __hip_bfloat16*)curA;
        const __hip_bfloat16* B = (const __hip_bfloat16*)curB;
        bf16x8 af[4], bg[4];
        #pragma unroll
        for (int mi = 0; mi < 4; ++mi)
            af[mi] = *(const bf16x8*)&A[ra0 + mi*16*32 + rdsw];
        #pragma unroll
        for (int ni = 0; ni < 4; ++ni)
            bg[ni] = *(const bf16x8*)&B[rb0 + ni*16*32 + rdsw];
        #pragma unroll
        for (int mi = 0; mi < 4; ++mi)
            #pragma unroll
            for (int ni = 0; ni < 4; ++ni)
                acc[mi][ni] = __builtin_amdgcn_mfma_f32_16x16x32_bf16(
                    af[mi], bg[ni], acc[mi][ni], 0, 0, 0);

        // rule-#18 fence pair: drain this wave's LDS reads and pin the schedule so
        // nothing (MFMA + its waits) sinks past the barrier; THEN barrier. Next
        // iteration's staging may overwrite this buffer only after all waves pass.
        asm volatile("s_waitcnt lgkmcnt(0)" ::: "memory");
        __builtin_amdgcn_sched_barrier(0);
        __builtin_amdgcn_s_barrier();
    }

    // ---- per-row partial maxima from acc regs (row = wm*64+mi*16+(lane>>4)*4+j) ----
    #pragma unroll
    for (int mi = 0; mi < 4; ++mi)
        #pragma unroll
        for (int j = 0; j < 4; ++j) {
            float mx = fmaxf(fmaxf(acc[mi][0][j], acc[mi][1][j]),
                             fmaxf(acc[mi][2][j], acc[mi][3][j]));
            #pragma unroll
            for (int o = 1; o < 16; o <<= 1) mx = fmaxf(mx, __shfl_xor(mx, o, 64));
            if ((lane & 15) == 0)
                Pmax[(wm*64 + mi*16 + (lane>>4)*4 + j)*2 + wn] = mx;
        }

    // ---- epilogue: LDS bounce -> coalesced full-row dwordx4 NONTEMPORAL stores ----
    const int cr = (lane >> 4) * 4;
    const int cc = lane & 15;
    #pragma unroll
    for (int c = 0; c < 2; ++c) {                    // chunk: rows [c*64, c*64+64)
        if (wm == c) {
            #pragma unroll
            for (int mi = 0; mi < 4; ++mi)
                #pragma unroll
                for (int ni = 0; ni < 4; ++ni) {
                    const int lrow = mi*16 + cr;                  // 0..63 within chunk
                    const int lcol = wn*64 + ni*16 + cc;          // 0..127
                    #pragma unroll
                    for (int j = 0; j < 4; ++j) {
                        float v = acc[mi][ni][j] * 0.0625f;
                        v = fminf(fmaxf(v, -16.0f), 16.0f);
                        Eps[(lrow + j) * 128 + lcol] = v;
                    }
                }
        }
        __syncthreads();   // bounce tile (and, first pass, Pmax) complete
        #pragma unroll
        for (int it = 0; it < 8; ++it) {
            const int p   = it * 1024 + t * 4;       // linear word index in [64][128]
            const int row = p >> 7;
            const int col = p & 127;
            float4 v = *(const float4*)&Eps[p];
            nt_store4(v, &Out[(size_t)(mb + c*64 + row) * 4096 + nb + col]);
        }
        __syncthreads();   // chunk read done before next chunk overwrites
    }

    // ---- Tmax: max is monotone under clamp(0.0625*x) -> equals max of stored values.
    if (t < 128) {
        float raw = fmaxf(Pmax[t*2], Pmax[t*2 + 1]);
        float v = raw * 0.0625f;
        v = fminf(fmaxf(v, -16.0f), 16.0f);
        Tmax[(size_t)(mb + t) * 32 + ctl] = v;
    }
}

// ---------------- FROZEN canonical fp32 dot (argmax determinism anchor) ----------------
// DO NOT change the summation structure. R3..R19 PASSED with this exact sequence.
__device__ __forceinline__ float dot256_f32(const float* __restrict__ a, const float* __restrict__ b)
{
    float s0 = 0.f, s1 = 0.f, s2 = 0.f, s3 = 0.f;
    #pragma unroll 8
    for (int j = 0; j < 64; ++j) {
        float4 x = ((const float4*)a)[j];
        float4 y = ((const float4*)b)[j];
        s0 = fmaf(x.x, y.x, s0);
        s1 = fmaf(x.y, y.y, s1);
        s2 = fmaf(x.z, y.z, s2);
        s3 = fmaf(x.w, y.w, s3);
    }
    return (s0 + s1) + (s2 + s3);
}

// ---------------- refine (fast): Tmax-pruned candidate scan + frozen dots ----------------
// Byte-identical to R19 (passed, ballot phase 2): nt stores for idx/z_q/z_q_2; Qf
// aliases Zq (reads complete before the aliased overwrite via the bi data dependence).
__global__ __launch_bounds__(256)
void refine_argmax_fast(const float* __restrict__ L, const float* __restrict__ Tmax,
                        const float* __restrict__ Qf, const float* __restrict__ Kf,
                        const float* __restrict__ Vf, float* __restrict__ OutIdx,
                        float* __restrict__ Zq, float* __restrict__ Zq2)
{
    __shared__ int cnt[4];
    __shared__ int list[4][256];
    const int lane = threadIdx.x & 63;
    const int w    = threadIdx.x >> 6;
    const size_t row = (size_t)blockIdx.x * 4 + w;

    // phase 1: row max from 32 tile maxima
    float tm = (lane < 32) ? Tmax[row * 32 + lane] : -INFINITY;
    float gmax = tm;
    #pragma unroll
    for (int o = 1; o < 64; o <<= 1) gmax = fmaxf(gmax, __shfl_xor(gmax, o, 64));
    const float thr = gmax - 0.5f;

    if (lane == 0) cnt[w] = 0;
    __syncthreads();   // unconditional

    // phase 2: ballot mask of candidate tiles, iterate set bits only (wave-uniform)
    unsigned long long cmask = __ballot(tm >= thr);   // lanes >=32: tm = -INF -> false
    while (cmask) {
        const int tile = __ffsll(cmask) - 1;
        cmask &= cmask - 1;
        const float2 v2 = *(const float2*)&L[row * 4096 + tile * 128 + lane * 2];
        if (v2.x >= thr) {
            int slot = atomicAdd(&cnt[w], 1);
            if (slot < 256) list[w][slot] = tile*128 + lane*2;
        }
        if (v2.y >= thr) {
            int slot = atomicAdd(&cnt[w], 1);
            if (slot < 256) list[w][slot] = tile*128 + lane*2 + 1;
        }
    }
    __syncthreads();   // unconditional

    // phase 3: one candidate per lane, all dots in ONE exec pass
    int m = cnt[w]; if (m > 256) m = 256;
    float bv = -INFINITY;
    int   bi = 0x7fffffff;
    const float* qrow = Qf + row * 256;
    for (int base = 0; base < m; base += 64) {
        const int ci = base + lane;
        if (ci < m) {
            const int c = list[w][ci];
            float rv = dot256_f32(qrow, Kf + (size_t)c * 256) * 0.0625f;
            if (rv > bv || (rv == bv && c < bi)) { bv = rv; bi = c; }
        }
    }
    #pragma unroll
    for (int o = 1; o < 64; o <<= 1) {
        float ov = __shfl_xor(bv, o, 64);
        int   oi = __shfl_xor(bi, o, 64);
        if (ov > bv || (ov == bv && oi < bi)) { bv = ov; bi = oi; }
    }

    if (bi < 0) bi = 0;
    if (bi > 4095) bi = 4095;

    if (lane == 0) __builtin_nontemporal_store((float)bi, &OutIdx[row]);

    float4 vv = ((const float4*)(Vf + (size_t)bi * 256))[lane];
    nt_store4(vv, (float*)&((float4*)Zq)[row*64 + lane]);
    nt_store4(vv, (float*)&((float4*)Zq2)[row*64 + lane]);
}

extern "C" void kernel_launch(void* const* d_in, const int* in_sizes, int n_in,
                              void* d_out, int out_size, void* d_ws, size_t ws_size,
                              hipStream_t stream)
{
    (void)in_sizes; (void)n_in; (void)out_size;
    const float* hs = (const float*)d_in[0];
    const float* cb = (const float*)d_in[1];
    const float* wq = (const float*)d_in[2];
    const float* bq = (const float*)d_in[3];
    const float* wk = (const float*)d_in[4];
    const float* bk = (const float*)d_in[5];
    const float* wv = (const float*)d_in[6];
    const float* bv = (const float*)d_in[7];
    const float* gq = (const float*)d_in[8];
    const float* gk = (const float*)d_in[9];
    float* out = (float*)d_out;   // fp32: reference outputs are fp32/int32

    if (ws_size < 31457280u) return;  // need 30MB scratch

    // d_out layout (floats): logits @0 [32768*4096], idx @134217728 [32768],
    // z_q @134250496 [32768*256], z_q_2 @142639104 [32768*256].
    float* qf = out + 134250496ull;   // q lives in the z_q region until the FINAL refine store

    char* ws = (char*)d_ws;
    float* kf = (float*)ws;                                   //  4 MB: k raw -> k_norm (in place)
    float* vf = (float*)(ws + 4194304);                       //  4 MB: v
    __hip_bfloat16* qb = (__hip_bfloat16*)(ws + 8388608);     // 16 MB: q_norm bf16
    __hip_bfloat16* kb = (__hip_bfloat16*)(ws + 25165824);    //  2 MB: k_norm bf16
    float* tmax = (float*)(ws + 27262976);                    //  4 MB: per-tile row max

    gemm_fused<<<dim3(320, 2), 256, 0, stream>>>(hs, cb, wq, bq, wk, bk, wv, bv,
                                                 qf, kf, vf);
    rmsnorm_fused<<<9216, 256, 0, stream>>>(kf, qf, gk, gq, kb, qb);
    mfma_logits<<<8192, 256, 0, stream>>>(qb, kb, out, tmax);
    refine_argmax_fast<<<8192, 256, 0, stream>>>(out, tmax, qf, kf, vf,
        out + 134217728ull,   // idx
        out + 134250496ull,   // z_q   (aliases qf by design)
        out + 142639104ull);  // z_q_2
}

// Round 22
// 401.819 us; speedup vs baseline: 4.4889x; 1.0552x over previous
//
#include <hip/hip_runtime.h>
#include <hip/hip_bf16.h>

// AttentionForQuantizer: q/k/v proj + RMSNorm + logits(32768x4096) + argmax + gather.
// R22: DRAM write-locality experiment. R21 (424us best) mfma is write-bound: 512MB /
// 149us = 3.4 TB/s vs 6.6 fill ceiling — 512B segments at 16KB stride lose DRAM page
// locality. Change: swap tile order within each XCD (mb from cid>>5, ctl from cid&31)
// so 32 CONSECUTIVE (temporally co-resident) blocks write the same 128 rows' different
// column segments -> memory controller assembles near-full 16KB rows. Same XCD keeps
// the same Q-band (L2 locality preserved). Per-tile compute bit-identical; pure index
// remap (bijective). All kernels otherwise byte-identical to R21 (passed).
// Canary: absmax == 0.03125.

#define NTOK 32768
#define NCODE 4096
#define DIM 256

typedef __bf16 bf16x8 __attribute__((ext_vector_type(8)));
typedef float f32x4 __attribute__((ext_vector_type(4)));

__device__ __forceinline__ void nt_store4(const float4& v, float* p) {
    f32x4 w; w[0] = v.x; w[1] = v.y; w[2] = v.z; w[3] = v.w;
    __builtin_nontemporal_store(w, (f32x4*)p);
}

// ---------------- fused fp32 GEMMs: k, v, q projections in one dispatch ----------------
// Byte-identical to R14/R19/R21 (passed). Grid (320, 2).
__global__ __launch_bounds__(256, 2)
void gemm_fused(const float* __restrict__ hs, const float* __restrict__ cb,
                const float* __restrict__ wq, const float* __restrict__ bq,
                const float* __restrict__ wk, const float* __restrict__ bk,
                const float* __restrict__ wv, const float* __restrict__ bv,
                float* __restrict__ qf, float* __restrict__ kf, float* __restrict__ vf)
{
    __shared__ __align__(16) float Xs[32][132];  // [kk][m], padded
    __shared__ __align__(16) float Ws[32][132];  // [kk][n], padded
    const int t  = threadIdx.x;
    const int tm = t >> 4;         // 0..15
    const int tn = t & 15;         // 0..15

    const int bx = blockIdx.x;
    const float* X; const float* W; const float* bias; float* Y; int mb;
    if (bx < 32)      { X = cb; W = wk; bias = bk; Y = kf; mb = bx * 128; }
    else if (bx < 64) { X = cb; W = wv; bias = bv; Y = vf; mb = (bx - 32) * 128; }
    else              { X = hs; W = wq; bias = bq; Y = qf; mb = (bx - 64) * 128; }
    const int nb = blockIdx.y * 128;

    float acc[8][8];
    #pragma unroll
    for (int i = 0; i < 8; ++i)
        #pragma unroll
        for (int j = 0; j < 8; ++j) acc[i][j] = 0.f;

    const int sxm = t >> 1;          // X staging: row 0..127
    const int sxh = (t & 1) * 16;    // X staging: k-half base
    const int swk = t >> 3;          // W staging: kk 0..31
    const int swc = (t & 7) * 16;    // W staging: col base

    for (int kb = 0; kb < 256; kb += 32) {
        float4 xv[4], wv4[4];
        #pragma unroll
        for (int i = 0; i < 4; ++i) {
            xv[i]  = *(const float4*)&X[(size_t)(mb + sxm) * 256 + kb + sxh + 4 * i];
            wv4[i] = *(const float4*)&W[(size_t)(kb + swk) * 256 + nb + swc + 4 * i];
        }
        __syncthreads();  // previous iteration's LDS reads done before overwrite
        #pragma unroll
        for (int i = 0; i < 4; ++i) {
            Xs[sxh + 4*i + 0][sxm] = xv[i].x;
            Xs[sxh + 4*i + 1][sxm] = xv[i].y;
            Xs[sxh + 4*i + 2][sxm] = xv[i].z;
            Xs[sxh + 4*i + 3][sxm] = xv[i].w;
            *(float4*)&Ws[swk][swc + 4*i] = wv4[i];
        }
        __syncthreads();
        #pragma unroll 8
        for (int kk = 0; kk < 32; ++kk) {
            float4 a0 = *(const float4*)&Xs[kk][tm*8];
            float4 a1 = *(const float4*)&Xs[kk][tm*8 + 4];
            float4 b0 = *(const float4*)&Ws[kk][tn*8];
            float4 b1 = *(const float4*)&Ws[kk][tn*8 + 4];
            float av[8] = {a0.x,a0.y,a0.z,a0.w,a1.x,a1.y,a1.z,a1.w};
            float bw[8] = {b0.x,b0.y,b0.z,b0.w,b1.x,b1.y,b1.z,b1.w};
            #pragma unroll
            for (int i = 0; i < 8; ++i)
                #pragma unroll
                for (int j = 0; j < 8; ++j)
                    acc[i][j] = fmaf(av[i], bw[j], acc[i][j]);
        }
    }

    float4 bb0 = *(const float4*)&bias[nb + tn*8];
    float4 bb1 = *(const float4*)&bias[nb + tn*8 + 4];
    float bb[8] = {bb0.x,bb0.y,bb0.z,bb0.w,bb1.x,bb1.y,bb1.z,bb1.w};
    #pragma unroll
    for (int i = 0; i < 8; ++i) {
        const size_t row = (size_t)(mb + tm*8 + i);
        float4 o0 = {acc[i][0]+bb[0], acc[i][1]+bb[1], acc[i][2]+bb[2], acc[i][3]+bb[3]};
        float4 o1 = {acc[i][4]+bb[4], acc[i][5]+bb[5], acc[i][6]+bb[6], acc[i][7]+bb[7]};
        *(float4*)&Y[row*256 + nb + tn*8]     = o0;
        *(float4*)&Y[row*256 + nb + tn*8 + 4] = o1;
    }
}

// ---------------- fused RMSNorm: k rows + q rows in one dispatch ----------------
// Byte-identical to R14/R19/R21 (passed). Grid 9216.
__global__ __launch_bounds__(256)
void rmsnorm_fused(float* __restrict__ kf, float* __restrict__ qf,
                   const float* __restrict__ gk, const float* __restrict__ gq,
                   __hip_bfloat16* __restrict__ kb, __hip_bfloat16* __restrict__ qb)
{
    const int b = blockIdx.x;
    float* X; const float* g; __hip_bfloat16* Xb; size_t row;
    if (b < 1024) { X = kf; g = gk; Xb = kb; row = (size_t)b * 4 + (threadIdx.x >> 6); }
    else { X = qf; g = gq; Xb = qb; row = (size_t)(b - 1024) * 4 + (threadIdx.x >> 6); }

    const int lane = threadIdx.x & 63;
    float4 x = *(const float4*)&X[row*256 + lane*4];
    float ssq = fmaf(x.x, x.x, fmaf(x.y, x.y, fmaf(x.z, x.z, x.w * x.w)));
    #pragma unroll
    for (int o = 1; o < 64; o <<= 1) ssq += __shfl_xor(ssq, o, 64);
    const float r = 1.0f / sqrtf(ssq * (1.0f/256.0f) + 1e-5f);
    float4 gg = *(const float4*)&g[lane*4];
    float y0 = (x.x*r)*gg.x, y1 = (x.y*r)*gg.y, y2 = (x.z*r)*gg.z, y3 = (x.w*r)*gg.w;
    float4 y = {y0, y1, y2, y3};
    *(float4*)&X[row*256 + lane*4] = y;
    __hip_bfloat16 h0 = __float2bfloat16(y0), h1 = __float2bfloat16(y1);
    __hip_bfloat16 h2 = __float2bfloat16(y2), h3 = __float2bfloat16(y3);
    ushort4 p;
    p.x = *(unsigned short*)&h0; p.y = *(unsigned short*)&h1;
    p.z = *(unsigned short*)&h2; p.w = *(unsigned short*)&h3;
    ((ushort4*)Xb)[row*64 + lane] = p;
}

// ---------------- bf16 MFMA logits: Out[32768][4096] = fp32(clamp(Q @ K^T * 1/16)) ----
// R22: tile-order swap — consecutive cid within an XCD now iterate COL-TILES of the
// same row-band (mb from cid>>5, ctl from cid&31), so co-resident blocks assemble
// near-full 16KB output rows for the DRAM controller. K-loop/staging/epilogue/Tmax
// byte-identical to R21 (passed); per-tile values bit-identical.
__device__ __forceinline__ void load_lds16(const void* g, void* l) {
    __builtin_amdgcn_global_load_lds((const __attribute__((address_space(1))) unsigned int*)g,
                                     (__attribute__((address_space(3))) unsigned int*)l, 16, 0, 0);
}

__global__ __launch_bounds__(256, 4)
void mfma_logits(const __hip_bfloat16* __restrict__ Qb, const __hip_bfloat16* __restrict__ Kb,
                 float* __restrict__ Out, float* __restrict__ Tmax)
{
    // 33KB: A0@0, B0@8192, A1@16384, B1@24576 (8KB each); Eps aliases 0..32KB; Pmax@32KB.
    __shared__ __align__(16) char smem[33792];
    float* Eps  = (float*)smem;
    float* Pmax = (float*)(smem + 32768);

    const int t    = threadIdx.x;
    const int lane = t & 63;
    const int w    = t >> 6;
    const int wm = w >> 1, wn = w & 1;      // 2x2 wave grid of 64x64 quadrants

    const int bid = blockIdx.x;
    const int xcd = bid & 7;
    const int cid = bid >> 3;                // 0..1023
    // R22 swap: row-band from cid>>5 (changes every 32 blocks), col-tile from cid&31
    // (changes every block) -> 32 consecutive blocks cover one band's full 4096 cols.
    const int mb  = (xcd * 32 + (cid >> 5)) * 128;
    const int ctl = cid & 31;                // col-tile 0..31
    const int nb  = ctl * 128;

    // staging source (per lane): row w*16 + (lane>>2) (+64 for issue 1),
    // chunk (lane&3)^((lane>>2)&3)  [involution; row&3 == (lane>>2)&3 for all issues]
    const int sr = w*16 + (lane >> 2);
    const int sc = (lane & 3) ^ ((lane >> 2) & 3);
    const __hip_bfloat16* gAr = Qb + (size_t)(mb + sr) * 256 + sc * 8;
    const __hip_bfloat16* gBr = Kb + (size_t)(nb + sr) * 256 + sc * 8;

    // fragment read geometry: row fr, k-chunk kq; swizzled slot kq^(fr&3)
    const int fr = lane & 15;
    const int kq = lane >> 4;
    const int rdsw = (kq ^ (fr & 3)) * 8;
    const int ra0 = (wm * 64 + fr) * 32;
    const int rb0 = (wn * 64 + fr) * 32;

    f32x4 acc[4][4];
    #pragma unroll
    for (int mi = 0; mi < 4; ++mi)
        #pragma unroll
        for (int ni = 0; ni < 4; ++ni) {
            acc[mi][ni][0] = 0.f; acc[mi][ni][1] = 0.f;
            acc[mi][ni][2] = 0.f; acc[mi][ni][3] = 0.f;
        }

    // ---- prologue: stage tile 0 into buf0 ----
    {
        char* dA = smem;            // A0
        char* dB = smem + 8192;     // B0
        load_lds16(gAr,             dA + w*1024);
        load_lds16(gAr + 64*256,    dA + 4096 + w*1024);
        load_lds16(gBr,             dB + w*1024);
        load_lds16(gBr + 64*256,    dB + 4096 + w*1024);
    }

    // ---- 8 pipelined K-steps (k = ks*32, ascending == R19/R21 per-element order) ----
    #pragma unroll
    for (int ks = 0; ks < 8; ++ks) {
        char* curA = (ks & 1) ? (smem + 16384) : smem;
        char* curB = (ks & 1) ? (smem + 24576) : (smem + 8192);
        if (ks < 7) {
            const int k0 = (ks + 1) * 32;
            char* nxtA = (ks & 1) ? smem : (smem + 16384);
            char* nxtB = (ks & 1) ? (smem + 8192) : (smem + 24576);
            load_lds16(gAr + k0,          nxtA + w*1024);
            load_lds16(gAr + 64*256 + k0, nxtA + 4096 + w*1024);
            load_lds16(gBr + k0,          nxtB + w*1024);
            load_lds16(gBr + 64*256 + k0, nxtB + 4096 + w*1024);
            asm volatile("s_waitcnt vmcnt(4)" ::: "memory");  // current tile landed
        } else {
            asm volatile("s_waitcnt vmcnt(0)" ::: "memory");  // final tile landed
        }
        __builtin_amdgcn_s_barrier();

        const __hip_bfloat16* A = (const __hip_bfloat16*)curA;
        const __hip_bfloat16* B = (const __hip_bfloat16*)curB;
        bf16x8 af[4], bg[4];
        #pragma unroll
        for (int mi = 0; mi < 4; ++mi)
            af[mi] = *(const bf16x8*)&A[ra0 + mi*16*32 + rdsw];
        #pragma unroll
        for (int ni = 0; ni < 4; ++ni)
            bg[ni] = *(const bf16x8*)&B[rb0 + ni*16*32 + rdsw];
        #pragma unroll
        for (int mi = 0; mi < 4; ++mi)
            #pragma unroll
            for (int ni = 0; ni < 4; ++ni)
                acc[mi][ni] = __builtin_amdgcn_mfma_f32_16x16x32_bf16(
                    af[mi], bg[ni], acc[mi][ni], 0, 0, 0);

        // rule-#18 fence pair: drain LDS reads + pin schedule, THEN barrier.
        asm volatile("s_waitcnt lgkmcnt(0)" ::: "memory");
        __builtin_amdgcn_sched_barrier(0);
        __builtin_amdgcn_s_barrier();
    }

    // ---- per-row partial maxima from acc regs (row = wm*64+mi*16+(lane>>4)*4+j) ----
    #pragma unroll
    for (int mi = 0; mi < 4; ++mi)
        #pragma unroll
        for (int j = 0; j < 4; ++j) {
            float mx = fmaxf(fmaxf(acc[mi][0][j], acc[mi][1][j]),
                             fmaxf(acc[mi][2][j], acc[mi][3][j]));
            #pragma unroll
            for (int o = 1; o < 16; o <<= 1) mx = fmaxf(mx, __shfl_xor(mx, o, 64));
            if ((lane & 15) == 0)
                Pmax[(wm*64 + mi*16 + (lane>>4)*4 + j)*2 + wn] = mx;
        }

    // ---- epilogue: LDS bounce -> coalesced full-row dwordx4 NONTEMPORAL stores ----
    const int cr = (lane >> 4) * 4;
    const int cc = lane & 15;
    #pragma unroll
    for (int c = 0; c < 2; ++c) {                    // chunk: rows [c*64, c*64+64)
        if (wm == c) {
            #pragma unroll
            for (int mi = 0; mi < 4; ++mi)
                #pragma unroll
                for (int ni = 0; ni < 4; ++ni) {
                    const int lrow = mi*16 + cr;                  // 0..63 within chunk
                    const int lcol = wn*64 + ni*16 + cc;          // 0..127
                    #pragma unroll
                    for (int j = 0; j < 4; ++j) {
                        float v = acc[mi][ni][j] * 0.0625f;
                        v = fminf(fmaxf(v, -16.0f), 16.0f);
                        Eps[(lrow + j) * 128 + lcol] = v;
                    }
                }
        }
        __syncthreads();   // bounce tile (and, first pass, Pmax) complete
        #pragma unroll
        for (int it = 0; it < 8; ++it) {
            const int p   = it * 1024 + t * 4;       // linear word index in [64][128]
            const int row = p >> 7;
            const int col = p & 127;
            float4 v = *(const float4*)&Eps[p];
            nt_store4(v, &Out[(size_t)(mb + c*64 + row) * 4096 + nb + col]);
        }
        __syncthreads();   // chunk read done before next chunk overwrites
    }

    // ---- Tmax: max is monotone under clamp(0.0625*x) -> equals max of stored values.
    if (t < 128) {
        float raw = fmaxf(Pmax[t*2], Pmax[t*2 + 1]);
        float v = raw * 0.0625f;
        v = fminf(fmaxf(v, -16.0f), 16.0f);
        Tmax[(size_t)(mb + t) * 32 + ctl] = v;
    }
}

// ---------------- FROZEN canonical fp32 dot (argmax determinism anchor) ----------------
// DO NOT change the summation structure. R3..R21 PASSED with this exact sequence.
__device__ __forceinline__ float dot256_f32(const float* __restrict__ a, const float* __restrict__ b)
{
    float s0 = 0.f, s1 = 0.f, s2 = 0.f, s3 = 0.f;
    #pragma unroll 8
    for (int j = 0; j < 64; ++j) {
        float4 x = ((const float4*)a)[j];
        float4 y = ((const float4*)b)[j];
        s0 = fmaf(x.x, y.x, s0);
        s1 = fmaf(x.y, y.y, s1);
        s2 = fmaf(x.z, y.z, s2);
        s3 = fmaf(x.w, y.w, s3);
    }
    return (s0 + s1) + (s2 + s3);
}

// ---------------- refine (fast): Tmax-pruned candidate scan + frozen dots ----------------
// Byte-identical to R19/R21 (passed, ballot phase 2): nt stores for idx/z_q/z_q_2; Qf
// aliases Zq (reads complete before the aliased overwrite via the bi data dependence).
__global__ __launch_bounds__(256)
void refine_argmax_fast(const float* __restrict__ L, const float* __restrict__ Tmax,
                        const float* __restrict__ Qf, const float* __restrict__ Kf,
                        const float* __restrict__ Vf, float* __restrict__ OutIdx,
                        float* __restrict__ Zq, float* __restrict__ Zq2)
{
    __shared__ int cnt[4];
    __shared__ int list[4][256];
    const int lane = threadIdx.x & 63;
    const int w    = threadIdx.x >> 6;
    const size_t row = (size_t)blockIdx.x * 4 + w;

    // phase 1: row max from 32 tile maxima
    float tm = (lane < 32) ? Tmax[row * 32 + lane] : -INFINITY;
    float gmax = tm;
    #pragma unroll
    for (int o = 1; o < 64; o <<= 1) gmax = fmaxf(gmax, __shfl_xor(gmax, o, 64));
    const float thr = gmax - 0.5f;

    if (lane == 0) cnt[w] = 0;
    __syncthreads();   // unconditional

    // phase 2: ballot mask of candidate tiles, iterate set bits only (wave-uniform)
    unsigned long long cmask = __ballot(tm >= thr);   // lanes >=32: tm = -INF -> false
    while (cmask) {
        const int tile = __ffsll(cmask) - 1;
        cmask &= cmask - 1;
        const float2 v2 = *(const float2*)&L[row * 4096 + tile * 128 + lane * 2];
        if (v2.x >= thr) {
            int slot = atomicAdd(&cnt[w], 1);
            if (slot < 256) list[w][slot] = tile*128 + lane*2;
        }
        if (v2.y >= thr) {
            int slot = atomicAdd(&cnt[w], 1);
            if (slot < 256) list[w][slot] = tile*128 + lane*2 + 1;
        }
    }
    __syncthreads();   // unconditional

    // phase 3: one candidate per lane, all dots in ONE exec pass
    int m = cnt[w]; if (m > 256) m = 256;
    float bv = -INFINITY;
    int   bi = 0x7fffffff;
    const float* qrow = Qf + row * 256;
    for (int base = 0; base < m; base += 64) {
        const int ci = base + lane;
        if (ci < m) {
            const int c = list[w][ci];
            float rv = dot256_f32(qrow, Kf + (size_t)c * 256) * 0.0625f;
            if (rv > bv || (rv == bv && c < bi)) { bv = rv; bi = c; }
        }
    }
    #pragma unroll
    for (int o = 1; o < 64; o <<= 1) {
        float ov = __shfl_xor(bv, o, 64);
        int   oi = __shfl_xor(bi, o, 64);
        if (ov > bv || (ov == bv && oi < bi)) { bv = ov; bi = oi; }
    }

    if (bi < 0) bi = 0;
    if (bi > 4095) bi = 4095;

    if (lane == 0) __builtin_nontemporal_store((float)bi, &OutIdx[row]);

    float4 vv = ((const float4*)(Vf + (size_t)bi * 256))[lane];
    nt_store4(vv, (float*)&((float4*)Zq)[row*64 + lane]);
    nt_store4(vv, (float*)&((float4*)Zq2)[row*64 + lane]);
}

extern "C" void kernel_launch(void* const* d_in, const int* in_sizes, int n_in,
                              void* d_out, int out_size, void* d_ws, size_t ws_size,
                              hipStream_t stream)
{
    (void)in_sizes; (void)n_in; (void)out_size;
    const float* hs = (const float*)d_in[0];
    const float* cb = (const float*)d_in[1];
    const float* wq = (const float*)d_in[2];
    const float* bq = (const float*)d_in[3];
    const float* wk = (const float*)d_in[4];
    const float* bk = (const float*)d_in[5];
    const float* wv = (const float*)d_in[6];
    const float* bv = (const float*)d_in[7];
    const float* gq = (const float*)d_in[8];
    const float* gk = (const float*)d_in[9];
    float* out = (float*)d_out;   // fp32: reference outputs are fp32/int32

    if (ws_size < 31457280u) return;  // need 30MB scratch

    // d_out layout (floats): logits @0 [32768*4096], idx @134217728 [32768],
    // z_q @134250496 [32768*256], z_q_2 @142639104 [32768*256].
    float* qf = out + 134250496ull;   // q lives in the z_q region until the FINAL refine store

    char* ws = (char*)d_ws;
    float* kf = (float*)ws;                                   //  4 MB: k raw -> k_norm (in place)
    float* vf = (float*)(ws + 4194304);                       //  4 MB: v
    __hip_bfloat16* qb = (__hip_bfloat16*)(ws + 8388608);     // 16 MB: q_norm bf16
    __hip_bfloat16* kb = (__hip_bfloat16*)(ws + 25165824);    //  2 MB: k_norm bf16
    float* tmax = (float*)(ws + 27262976);                    //  4 MB: per-tile row max

    gemm_fused<<<dim3(320, 2), 256, 0, stream>>>(hs, cb, wq, bq, wk, bk, wv, bv,
                                                 qf, kf, vf);
    rmsnorm_fused<<<9216, 256, 0, stream>>>(kf, qf, gk, gq, kb, qb);
    mfma_logits<<<8192, 256, 0, stream>>>(qb, kb, out, tmax);
    refine_argmax_fast<<<8192, 256, 0, stream>>>(out, tmax, qf, kf, vf,
        out + 134217728ull,   // idx
        out + 134250496ull,   // z_q   (aliases qf by design)
        out + 142639104ull);  // z_q_2
}